// Round 6
// baseline (448.547 us; speedup 1.0000x reference)
//
#include <hip/hip_runtime.h>
#include <hip/hip_bf16.h>
#include <stdint.h>
#include <cmath>

// IDXST_IDCT on MI355X: y = S · x · C^T with
//   C[v,q] = cos(pi*q*(2v+1)/(2N)),  S[u,p] = sin(pi*p*(2u+1)/(2M))
// Butterfly halves GEMM FLOPs (dual E/O accumulators, fused epilogue).
// R12: R10 geometry (BM=BN=128, BK=64, 256 thr / 4 waves, 64 KB LDS,
// 2 blocks/CU) + 4-phase register-prefetch schedule. Each phase issues the
// NEXT phase's 8 ds_read_b128 then runs the CURRENT 16 MFMAs (operands
// read a full phase earlier -> lgkm waits ~free; LDS pipe never drains
// behind MFMA). Barriers only at buffer hand-offs; vmcnt(8) always covered
// by >=2 phases; never vmcnt(0) mid-loop. R11's regression (BK=32) came
// from 64B row granule (HBM overfetch, FETCH 140->167MB) + uncovered
// vmcnt(0) per tiny tile — both reverted here.
// K-order/acc chain bit-identical to R10 -> absmax must stay 64.0.
// XOR-swizzled LDS (verified zero bank conflicts), XCD-aware block swizzle.
// 3 dispatches total: prep, F1 (GEMM+bfly1+deint), F2 (GEMM+bfly2).

typedef __attribute__((ext_vector_type(4))) float f32x4;
typedef __attribute__((ext_vector_type(8))) unsigned short u16x8;
typedef __attribute__((ext_vector_type(8))) __bf16 bf16x8;

__device__ __forceinline__ unsigned short f2bf(float f) {
  union { float f; unsigned u; } v; v.f = f;
  unsigned u = v.u + 0x7fffu + ((v.u >> 16) & 1u);  // RNE
  return (unsigned short)(u >> 16);
}

// ---- gen device helper: half transform matrices [L/2 x L/2] bf16 ----
// Pe[i,j] = f(pi*(2j)(2i+1)/(2L)), Po[i,j] = f(pi*(2j+1)(2i+1)/(2L)).
// r tracked mod 4L (power of two -> exact in u32).
__device__ __forceinline__ void gen_half(int idx, u16x8* Pe, u16x8* Po,
                                         int isSin, int jshift, int jmask,
                                         unsigned mask4L, float sc) {
  int i = idx >> jshift;           // row
  int jb = (idx & jmask) * 8;      // first col
  unsigned tp = 2u * (unsigned)i + 1u;
  unsigned re = (2u * (unsigned)jb * tp) & mask4L;
  unsigned ro = (re + tp) & mask4L;
  unsigned step = (2u * tp) & mask4L;
  u16x8 pe, po;
#pragma unroll
  for (int t = 0; t < 8; t++) {
    float se_, ce_, so_, co_;
    __sincosf((float)re * sc, &se_, &ce_);
    __sincosf((float)ro * sc, &so_, &co_);
    pe[t] = f2bf(isSin ? se_ : ce_);
    po[t] = f2bf(isSin ? so_ : co_);
    re = (re + step) & mask4L;
    ro = (ro + step) & mask4L;
  }
  Pe[idx] = pe;
  Po[idx] = po;
}

// ---- single prep dispatch: convert+deint | gen Ce/Co | gen Se/So ----
__global__ void prep_kernel(const f32x4* __restrict__ x, u16x8* __restrict__ xe,
                            u16x8* __restrict__ xo, u16x8* __restrict__ Ce,
                            u16x8* __restrict__ Co, u16x8* __restrict__ Se,
                            u16x8* __restrict__ So, int nConvBlocks,
                            int nGenNBlocks, int jshiftN, int jmaskN,
                            unsigned mask4N, float scN, int jshiftM, int jmaskM,
                            unsigned mask4M, float scM) {
  int b = blockIdx.x;
  if (b < nConvBlocks) {
    int idx = b * 256 + threadIdx.x;
    f32x4 a = x[4 * idx], bb = x[4 * idx + 1], c = x[4 * idx + 2],
          d = x[4 * idx + 3];
    u16x8 e, o;
    e[0] = f2bf(a[0]);  o[0] = f2bf(a[1]);  e[1] = f2bf(a[2]);  o[1] = f2bf(a[3]);
    e[2] = f2bf(bb[0]); o[2] = f2bf(bb[1]); e[3] = f2bf(bb[2]); o[3] = f2bf(bb[3]);
    e[4] = f2bf(c[0]);  o[4] = f2bf(c[1]);  e[5] = f2bf(c[2]);  o[5] = f2bf(c[3]);
    e[6] = f2bf(d[0]);  o[6] = f2bf(d[1]);  e[7] = f2bf(d[2]);  o[7] = f2bf(d[3]);
    xe[idx] = e;
    xo[idx] = o;
  } else if (b < nConvBlocks + nGenNBlocks) {
    int idx = (b - nConvBlocks) * 256 + threadIdx.x;
    gen_half(idx, Ce, Co, 0, jshiftN, jmaskN, mask4N, scN);
  } else {
    int idx = (b - nConvBlocks - nGenNBlocks) * 256 + threadIdx.x;
    gen_half(idx, Se, So, 1, jshiftM, jmaskM, mask4M, scM);
  }
}

#define LGKM8()                                             \
  do {                                                      \
    asm volatile("s_waitcnt lgkmcnt(8)" ::: "memory");      \
    __builtin_amdgcn_sched_barrier(0);                      \
  } while (0)
#define LGKM0()                                             \
  do {                                                      \
    asm volatile("s_waitcnt lgkmcnt(0)" ::: "memory");      \
    __builtin_amdgcn_sched_barrier(0);                      \
  } while (0)
#define VMCNT8()                                            \
  do {                                                      \
    asm volatile("s_waitcnt vmcnt(8)" ::: "memory");        \
    __builtin_amdgcn_sched_barrier(0);                      \
  } while (0)
#define VMCNT0()                                            \
  do {                                                      \
    asm volatile("s_waitcnt vmcnt(0)" ::: "memory");        \
    __builtin_amdgcn_sched_barrier(0);                      \
  } while (0)
#define BAR() __builtin_amdgcn_s_barrier()

// ---- fused dual bt-GEMM + butterfly epilogue, 4-phase reg-prefetch ----
// accE[m,n] = sum_k Ae[m,k]*Be[n,k]; accO likewise with Ao/Bo.
// BM=BN=128, BK=64, 256 threads (4 waves of 64x64; 2m x 2n), 2 blocks/CU.
// LDS: elem (row,col) at row*64 + ((col/8)^(row&7))*8 + col%8; staging lane l
// sources global col ((l&7)^(l>>3))*8 so dst stays wave-uniform-base+lane*16.
// Per iter: P0{rd eh1; lgkm8; mfma eh0}  P1{lgkm0; BAR; stageE'; vm8; BAR;
// rd oh0; mfma eh1}  P2{rd oh1; lgkm8; mfma oh0}  P3{lgkm0; BAR; stageO';
// vm8; BAR; rd eh0'; mfma oh1}.  All lgkm waits cover reads issued a full
// phase earlier; vmcnt(8) covers loads issued >=2 phases earlier.
// STAGE==1 (m=v, n=p): (p&1?out1:out0)[v, p>>1] = E+O;
//                      [...][Lfull-1-v, p>>1]   = E-O   (bf16)
// STAGE==2 (m=u, n=v): y[u,v] = E+O; y[Lfull-1-u,v] = O-E  (fp32, out0)
template <int STAGE>
__global__ __launch_bounds__(256, 2) void fused_gemm_kernel(
    const unsigned short* __restrict__ Ae,
    const unsigned short* __restrict__ Ao,
    const unsigned short* __restrict__ Be,
    const unsigned short* __restrict__ Bo,
    unsigned short* __restrict__ out0, unsigned short* __restrict__ out1,
    int outStride, int K, int Lfull) {
  __shared__ unsigned short AsE[128 * 64];
  __shared__ unsigned short BsE[128 * 64];
  __shared__ unsigned short AsO[128 * 64];
  __shared__ unsigned short BsO[128 * 64];

  const int tid = threadIdx.x;

  // XCD-aware bijective block swizzle (nwg = 512, nwg%8 == 0).
  const int nwg = gridDim.x * gridDim.y;
  const int lin = blockIdx.y * gridDim.x + blockIdx.x;
  int swb = lin;
  if ((nwg & 7) == 0) swb = (lin & 7) * (nwg >> 3) + (lin >> 3);
  const int m0 = (swb / gridDim.x) * 128;
  const int n0 = (swb % gridDim.x) * 128;

  const int wave = tid >> 6;
  const int lane = tid & 63;
  const int wm = (wave & 1) * 64;   // 2 m-waves
  const int wn = (wave >> 1) * 64;  // 2 n-waves
  const int l16 = lane & 15;
  const int quad = lane >> 4;
  const int swz = (quad ^ (l16 & 7)) * 8;  // frag col swizzle, k-half 0

  // staging: chunk = 8 rows x 64 cols = 1 KB = one wave-wide global_load_lds.
  // Each wave loads A-chunks {wave+4t} and B-chunks {wave+4t}, t=0..3.
  const int lrow = lane >> 3;                // row within chunk
  const int lsw = ((lane & 7) ^ lrow) * 8;   // swizzled source col (elems)

  auto stageP = [&](const unsigned short* __restrict__ A,
                    const unsigned short* __restrict__ B, unsigned short* As,
                    unsigned short* Bs, int k0) {
#define GLL(src, dst)                                                        \
  __builtin_amdgcn_global_load_lds(                                          \
      (const __attribute__((address_space(1))) void*)(src),                  \
      (__attribute__((address_space(3))) void*)(dst), 16, 0, 0)
#pragma unroll
    for (int t = 0; t < 4; t++) {
      int ch = wave + 4 * t;
      GLL(A + (size_t)(m0 + 8 * ch + lrow) * K + lsw + k0, As + ch * 512);
      GLL(B + (size_t)(n0 + 8 * ch + lrow) * K + lsw + k0, Bs + ch * 512);
    }
#undef GLL
  };

  f32x4 accE[4][4], accO[4][4];
#pragma unroll
  for (int i = 0; i < 4; i++)
#pragma unroll
    for (int j = 0; j < 4; j++) {
      accE[i][j] = f32x4{0.f, 0.f, 0.f, 0.f};
      accO[i][j] = f32x4{0.f, 0.f, 0.f, 0.f};
    }

  // issue one k-half's 8 frag reads (4 A + 4 B) into regs
  auto readF = [&](const unsigned short* As, const unsigned short* Bs, int h,
                   bf16x8 (&fa)[4], bf16x8 (&fb)[4]) {
    const int so = swz ^ (h * 32);
#pragma unroll
    for (int i = 0; i < 4; i++)
      fa[i] = *(const bf16x8*)(As + (wm + i * 16 + l16) * 64 + so);
#pragma unroll
    for (int j = 0; j < 4; j++)
      fb[j] = *(const bf16x8*)(Bs + (wn + j * 16 + l16) * 64 + so);
  };

  auto mfma16 = [&](bf16x8 (&fa)[4], bf16x8 (&fb)[4], f32x4 (&acc)[4][4]) {
    __builtin_amdgcn_s_setprio(1);
#pragma unroll
    for (int i = 0; i < 4; i++)
#pragma unroll
      for (int j = 0; j < 4; j++)
        acc[i][j] = __builtin_amdgcn_mfma_f32_16x16x32_bf16(
            fa[i], fb[j], acc[i][j], 0, 0, 0);
    __builtin_amdgcn_s_setprio(0);
  };

  bf16x8 ea[4], eb[4], ea1[4], eb1[4];
  bf16x8 oa[4], ob[4], oa1[4], ob1[4];

  // prologue: E(0) + O(0) in flight; confirm E(0); prefetch eh0.
  stageP(Ae, Be, AsE, BsE, 0);
  stageP(Ao, Bo, AsO, BsO, 0);
  VMCNT8();                      // E(0) own-landed (O(0) stays in flight)
  BAR();                         // E(0) collective
  readF(AsE, BsE, 0, ea, eb);    // eh0 reads issued

  // invariant at iter top: E(k) collective-landed, O(k) own-in-flight(8),
  // eh0 reads issued (8 pending lgkm).
  for (int k0 = 0; k0 < K; k0 += 64) {
    const bool lastIt = (k0 + 64 >= K);

    // P0
    readF(AsE, BsE, 1, ea1, eb1);   // eh1 issue (lgkm pend 16)
    LGKM8();                        // eh0 ready
    mfma16(ea, eb, accE);
    // P1
    LGKM0();                        // eh1 ready; all E reads retired
    BAR();                          // E bufs free (collective)
    if (!lastIt) {
      stageP(Ae, Be, AsE, BsE, k0 + 64);  // vm pend: O(k) 8 + E' 8
      VMCNT8();                           // O(k) own-landed
    } else {
      VMCNT0();                           // drain O(k)
    }
    BAR();                          // O(k) collective
    readF(AsO, BsO, 0, oa, ob);     // oh0 issue
    mfma16(ea1, eb1, accE);
    // P2
    readF(AsO, BsO, 1, oa1, ob1);   // oh1 issue (lgkm pend 16)
    LGKM8();                        // oh0 ready
    mfma16(oa, ob, accO);
    // P3
    LGKM0();                        // oh1 ready; all O reads retired
    BAR();                          // O bufs free (collective)
    if (!lastIt) {
      stageP(Ao, Bo, AsO, BsO, k0 + 64);  // vm pend: E' 8 + O' 8
      VMCNT8();                           // E' own-landed
    } else {
      VMCNT0();
    }
    BAR();                          // E(k+64) collective
    if (!lastIt) readF(AsE, BsE, 0, ea, eb);  // eh0' issue
    mfma16(oa1, ob1, accO);
  }

  // epilogue: D row = quad*4 + reg, col = lane&15; butterfly E/O in fp32
#pragma unroll
  for (int i = 0; i < 4; i++) {
#pragma unroll
    for (int j = 0; j < 4; j++) {
      int n = n0 + wn + j * 16 + l16;
      int mb = m0 + wm + i * 16 + quad * 4;
#pragma unroll
      for (int r = 0; r < 4; r++) {
        float e = accE[i][j][r];
        float o = accO[i][j][r];
        int m = mb + r;
        if (STAGE == 1) {
          unsigned short* mat = (n & 1) ? out1 : out0;
          int c = n >> 1;
          mat[(size_t)m * outStride + c] = f2bf(e + o);
          mat[(size_t)(Lfull - 1 - m) * outStride + c] = f2bf(e - o);
        } else {
          float* y = (float*)out0;
          y[(size_t)m * outStride + n] = e + o;
          y[(size_t)(Lfull - 1 - m) * outStride + n] = o - e;
        }
      }
    }
  }
}

extern "C" void kernel_launch(void* const* d_in, const int* in_sizes, int n_in,
                              void* d_out, int out_size, void* d_ws,
                              size_t ws_size, hipStream_t stream) {
  const float* x = (const float*)d_in[0];
  const int M = in_sizes[1] / 2;  // expkM is [M,2]
  const int N = in_sizes[2] / 2;  // expkN is [N,2]
  const size_t MN = (size_t)M * N;

  // workspace (u16 units), 3*MN u16 = 96 MB @4096:
  //  [0, MN/2)      xe  [M x N/2]
  //  [MN/2, MN)     xo  [M x N/2]
  //  [MN, 5MN/4)    Ce ; [5MN/4, 3MN/2) Co     [N/2 x N/2]
  //  [3MN/2, 7MN/4) Se ; [7MN/4, 2MN)   So     [M/2 x M/2]
  //  [2MN, 5MN/2)   tTe [N x M/2]
  //  [5MN/2, 3MN)   tTo [N x M/2]
  unsigned short* ws = (unsigned short*)d_ws;
  unsigned short* xe = ws;
  unsigned short* xo = ws + MN / 2;
  unsigned short* Ce = ws + MN;
  unsigned short* Co = ws + MN + MN / 4;
  unsigned short* Se = ws + MN * 3 / 2;
  unsigned short* So = ws + MN * 7 / 4;
  unsigned short* tTe = ws + MN * 2;
  unsigned short* tTo = ws + MN * 5 / 2;

  int shiftN = 0; while ((1 << shiftN) < N) shiftN++;
  int shiftM = 0; while ((1 << shiftM) < M) shiftM++;

  // 1: fused prep — convert+deint, gen Ce/Co, gen Se/So
  int nConvBlocks = (int)(MN / 16 / 256);
  int nGenNBlocks = (N / 2) * (N / 2) / 8 / 256;
  int nGenMBlocks = (M / 2) * (M / 2) / 8 / 256;
  prep_kernel<<<nConvBlocks + nGenNBlocks + nGenMBlocks, 256, 0, stream>>>(
      (const f32x4*)x, (u16x8*)xe, (u16x8*)xo, (u16x8*)Ce, (u16x8*)Co,
      (u16x8*)Se, (u16x8*)So, nConvBlocks, nGenNBlocks, shiftN - 4,
      (N / 16) - 1, (unsigned)(4 * N - 1),
      (float)(3.14159265358979323846 / (2.0 * N)), shiftM - 4, (M / 16) - 1,
      (unsigned)(4 * M - 1), (float)(3.14159265358979323846 / (2.0 * M)));

  // 2: F1 — E/O GEMMs (K=N/2) + v-butterfly + p-parity deint -> tTe/tTo
  //    grid: x over p (M/128), y over v' ((N/2)/128); 256 threads
  fused_gemm_kernel<1><<<dim3(M / 128, (N / 2) / 128), 256, 0, stream>>>(
      Ce, Co, xe, xo, tTe, tTo, M / 2, N / 2, N);

  // 3: F2 — E/O GEMMs (K=M/2) + u-butterfly -> y fp32
  //    grid: x over v (N/128), y over u' ((M/2)/128); 256 threads
  fused_gemm_kernel<2><<<dim3(N / 128, (M / 2) / 128), 256, 0, stream>>>(
      Se, So, tTe, tTo, (unsigned short*)d_out, nullptr, N, M / 2, M);
}

// Round 7
// 311.137 us; speedup vs baseline: 1.4416x; 1.4416x over previous
//
#include <hip/hip_runtime.h>
#include <hip/hip_bf16.h>
#include <stdint.h>
#include <cmath>

// IDXST_IDCT on MI355X: y = S · x · C^T with
//   C[v,q] = cos(pi*q*(2v+1)/(2N)),  S[u,p] = sin(pi*p*(2u+1)/(2M))
// Butterfly halves GEMM FLOPs (dual E/O accumulators, fused epilogue).
// R13: parity-split waves with asymmetric 128x64 wave tiles. Block 128x128,
// 4 waves: w0,w1 = E-parity (col-halves 0,1), w2,w3 = O-parity. Each wave
// reads 24KB/iter from LDS for 2x the FLOPs of R10's 64x64 dual-parity
// waves -> 25% fewer ds_read_b128 (R10 was LDS-pipe bound at 69% busy).
// LDS 64KB (2 blocks/CU): per matrix [2 k-halves][128][32] bf16, R11's
// verified swizzle (phys slot = quad ^ ((row>>1)&3)); global rows stay
// 128B (both halves staged same iter -> L2 absorbs the 64B splits).
// K-loop: 2 half-phases/iter {vmcnt(8); bar; 12 ds_reads; lgkm0; bar;
// stage next half (8 GLL); 32 MFMA setprio}. No deep reg-prefetch (R12
// spilled: WRITE_SIZE 33->139MB scratch). Butterfly via one-time LDS
// exchange: O-waves write acc (XOR-swizzled f32 [col][128]), E-waves
// combine + store both outputs. Per-parity MFMA order bit-identical to
// R10 -> absmax must stay exactly 64.0.
// 3 dispatches total: prep, F1 (GEMM+bfly1+deint), F2 (GEMM+bfly2).

typedef __attribute__((ext_vector_type(4))) float f32x4;
typedef __attribute__((ext_vector_type(8))) unsigned short u16x8;
typedef __attribute__((ext_vector_type(8))) __bf16 bf16x8;

__device__ __forceinline__ unsigned short f2bf(float f) {
  union { float f; unsigned u; } v; v.f = f;
  unsigned u = v.u + 0x7fffu + ((v.u >> 16) & 1u);  // RNE
  return (unsigned short)(u >> 16);
}

// ---- gen device helper: half transform matrices [L/2 x L/2] bf16 ----
__device__ __forceinline__ void gen_half(int idx, u16x8* Pe, u16x8* Po,
                                         int isSin, int jshift, int jmask,
                                         unsigned mask4L, float sc) {
  int i = idx >> jshift;           // row
  int jb = (idx & jmask) * 8;      // first col
  unsigned tp = 2u * (unsigned)i + 1u;
  unsigned re = (2u * (unsigned)jb * tp) & mask4L;
  unsigned ro = (re + tp) & mask4L;
  unsigned step = (2u * tp) & mask4L;
  u16x8 pe, po;
#pragma unroll
  for (int t = 0; t < 8; t++) {
    float se_, ce_, so_, co_;
    __sincosf((float)re * sc, &se_, &ce_);
    __sincosf((float)ro * sc, &so_, &co_);
    pe[t] = f2bf(isSin ? se_ : ce_);
    po[t] = f2bf(isSin ? so_ : co_);
    re = (re + step) & mask4L;
    ro = (ro + step) & mask4L;
  }
  Pe[idx] = pe;
  Po[idx] = po;
}

// ---- single prep dispatch: convert+deint | gen Ce/Co | gen Se/So ----
__global__ void prep_kernel(const f32x4* __restrict__ x, u16x8* __restrict__ xe,
                            u16x8* __restrict__ xo, u16x8* __restrict__ Ce,
                            u16x8* __restrict__ Co, u16x8* __restrict__ Se,
                            u16x8* __restrict__ So, int nConvBlocks,
                            int nGenNBlocks, int jshiftN, int jmaskN,
                            unsigned mask4N, float scN, int jshiftM, int jmaskM,
                            unsigned mask4M, float scM) {
  int b = blockIdx.x;
  if (b < nConvBlocks) {
    int idx = b * 256 + threadIdx.x;
    f32x4 a = x[4 * idx], bb = x[4 * idx + 1], c = x[4 * idx + 2],
          d = x[4 * idx + 3];
    u16x8 e, o;
    e[0] = f2bf(a[0]);  o[0] = f2bf(a[1]);  e[1] = f2bf(a[2]);  o[1] = f2bf(a[3]);
    e[2] = f2bf(bb[0]); o[2] = f2bf(bb[1]); e[3] = f2bf(bb[2]); o[3] = f2bf(bb[3]);
    e[4] = f2bf(c[0]);  o[4] = f2bf(c[1]);  e[5] = f2bf(c[2]);  o[5] = f2bf(c[3]);
    e[6] = f2bf(d[0]);  o[6] = f2bf(d[1]);  e[7] = f2bf(d[2]);  o[7] = f2bf(d[3]);
    xe[idx] = e;
    xo[idx] = o;
  } else if (b < nConvBlocks + nGenNBlocks) {
    int idx = (b - nConvBlocks) * 256 + threadIdx.x;
    gen_half(idx, Ce, Co, 0, jshiftN, jmaskN, mask4N, scN);
  } else {
    int idx = (b - nConvBlocks - nGenNBlocks) * 256 + threadIdx.x;
    gen_half(idx, Se, So, 1, jshiftM, jmaskM, mask4M, scM);
  }
}

#define LGKM0()                                             \
  do {                                                      \
    asm volatile("s_waitcnt lgkmcnt(0)" ::: "memory");      \
    __builtin_amdgcn_sched_barrier(0);                      \
  } while (0)
#define VMCNT8()                                            \
  do {                                                      \
    asm volatile("s_waitcnt vmcnt(8)" ::: "memory");        \
    __builtin_amdgcn_sched_barrier(0);                      \
  } while (0)
#define VMCNT0()                                            \
  do {                                                      \
    asm volatile("s_waitcnt vmcnt(0)" ::: "memory");        \
    __builtin_amdgcn_sched_barrier(0);                      \
  } while (0)
#define BAR() __builtin_amdgcn_s_barrier()

// ---- fused dual bt-GEMM + butterfly, parity-split asymmetric waves ----
// accE[m,n] = sum_k Ae[m,k]*Be[n,k]; accO likewise (E by waves 0-1, O by
// waves 2-3; each wave owns 128 rows x 64 cols of the 128x128 block).
// LDS per matrix: [half][row][32] bf16; elem (row,col): half = col/32,
// slot = (col%32)/8, phys slot = slot ^ ((row>>1)&3)  (R11-verified).
// Staging chunk = 16 rows x 32 cols; lane l -> row l>>2, source col
// (32*half + ((l&3)^((l>>3)&3))*8)  — linear LDS dst (rule #21).
// STAGE==1 (m=v, n=p): (p&1?out1:out0)[v, p>>1] = E+O;
//                      [...][Lfull-1-v, p>>1]   = E-O   (bf16)
// STAGE==2 (m=u, n=v): y[u,v] = E+O; y[Lfull-1-u,v] = O-E  (fp32, out0)
template <int STAGE>
__global__ __launch_bounds__(256, 2) void fused_gemm_kernel(
    const unsigned short* __restrict__ Ae,
    const unsigned short* __restrict__ Ao,
    const unsigned short* __restrict__ Be,
    const unsigned short* __restrict__ Bo,
    unsigned short* __restrict__ out0, unsigned short* __restrict__ out1,
    int outStride, int K, int Lfull) {
  __shared__ unsigned short lds[4 * 8192];  // 64 KB
  unsigned short* AsE = lds;
  unsigned short* BsE = lds + 8192;
  unsigned short* AsO = lds + 16384;
  unsigned short* BsO = lds + 24576;

  const int tid = threadIdx.x;

  // XCD-aware bijective block swizzle (nwg = 512, nwg%8 == 0).
  const int nwg = gridDim.x * gridDim.y;
  const int lin = blockIdx.y * gridDim.x + blockIdx.x;
  int swb = lin;
  if ((nwg & 7) == 0) swb = (lin & 7) * (nwg >> 3) + (lin >> 3);
  const int m0 = (swb / gridDim.x) * 128;
  const int n0 = (swb % gridDim.x) * 128;

  const int wave = tid >> 6;
  const int lane = tid & 63;
  const int isO = (wave >> 1) & 1;  // 0 = E-waves, 1 = O-waves
  const int hw = wave & 1;          // col-half of the wave
  const int l16 = lane & 15;
  const int quad = lane >> 4;
  // frag read swizzle within a 32-col half (R11-verified):
  const int so = (quad ^ ((l16 >> 1) & 3)) * 8;  // elem offset in 32-col row

  // staging: chunk = 16 rows x 32 cols = 1 KB; lane l -> row l>>2,
  // source col ((l&3)^((l>>3)&3))*8 (pre-swizzled; linear LDS dst).
  const int srow = lane >> 2;
  const int scol = ((lane & 3) ^ ((lane >> 3) & 3)) * 8;

  // per-wave parity operand pointers
  const unsigned short* Aw = isO ? Ao : Ae;
  const unsigned short* Bw = isO ? Bo : Be;
  unsigned short* AsW = isO ? AsO : AsE;
  unsigned short* BsW = isO ? BsO : BsE;

  // stage one k-half (32 cols) of next tile for ALL 4 matrices.
  // wave stages chunks {wave, wave+4} of each matrix: 8 GLL.
  auto stageH = [&](int k0, int h) {
#define GLL(src, dst)                                                        \
  __builtin_amdgcn_global_load_lds(                                          \
      (const __attribute__((address_space(1))) void*)(src),                  \
      (__attribute__((address_space(3))) void*)(dst), 16, 0, 0)
    const int kc = k0 + 32 * h + scol;
    const int hb = h * 4096;
#pragma unroll
    for (int t = 0; t < 2; t++) {
      const int ch = wave + 4 * t;
      const int row = 16 * ch + srow;
      GLL(Ae + (size_t)(m0 + row) * K + kc, AsE + hb + ch * 512);
      GLL(Be + (size_t)(n0 + row) * K + kc, BsE + hb + ch * 512);
      GLL(Ao + (size_t)(m0 + row) * K + kc, AsO + hb + ch * 512);
      GLL(Bo + (size_t)(n0 + row) * K + kc, BsO + hb + ch * 512);
    }
#undef GLL
  };

  f32x4 acc[8][4];
#pragma unroll
  for (int i = 0; i < 8; i++)
#pragma unroll
    for (int j = 0; j < 4; j++) acc[i][j] = f32x4{0.f, 0.f, 0.f, 0.f};

  // one half-phase of compute: 12 frag reads (own parity), lgkm0, 32 MFMA
  auto computeH = [&](int h) {
    const int hb = h * 4096;
    bf16x8 fa[8], fb[4];
#pragma unroll
    for (int i = 0; i < 8; i++)
      fa[i] = *(const bf16x8*)(AsW + hb + (i * 16 + l16) * 32 + so);
#pragma unroll
    for (int j = 0; j < 4; j++)
      fb[j] = *(const bf16x8*)(BsW + hb + (64 * hw + j * 16 + l16) * 32 + so);
    LGKM0();
    __builtin_amdgcn_s_setprio(1);
#pragma unroll
    for (int i = 0; i < 8; i++)
#pragma unroll
      for (int j = 0; j < 4; j++)
        acc[i][j] = __builtin_amdgcn_mfma_f32_16x16x32_bf16(
            fa[i], fb[j], acc[i][j], 0, 0, 0);
    __builtin_amdgcn_s_setprio(0);
  };

  // prologue: stage k=0 halves 0 and 1 (16 loads in flight)
  stageH(0, 0);
  stageH(0, 1);

  for (int k0 = 0; k0 < K; k0 += 64) {
    const bool lastIt = (k0 + 64 >= K);

    // phase h0
    VMCNT8();                 // (k0,h0) landed own; (k0,h1) stays in flight
    BAR();                    // collective
    {
      const int hb = 0;
      (void)hb;
    }
    // reads + lgkm0 + bar must precede overwrite of this half
    {
      bf16x8 fa[8], fb[4];
#pragma unroll
      for (int i = 0; i < 8; i++)
        fa[i] = *(const bf16x8*)(AsW + (i * 16 + l16) * 32 + so);
#pragma unroll
      for (int j = 0; j < 4; j++)
        fb[j] = *(const bf16x8*)(BsW + (64 * hw + j * 16 + l16) * 32 + so);
      LGKM0();
      BAR();                  // all waves' h0 reads retired -> h0 free
      if (!lastIt) stageH(k0 + 64, 0);
      __builtin_amdgcn_s_setprio(1);
#pragma unroll
      for (int i = 0; i < 8; i++)
#pragma unroll
        for (int j = 0; j < 4; j++)
          acc[i][j] = __builtin_amdgcn_mfma_f32_16x16x32_bf16(
              fa[i], fb[j], acc[i][j], 0, 0, 0);
      __builtin_amdgcn_s_setprio(0);
    }

    // phase h1
    if (!lastIt) {
      VMCNT8();               // (k0,h1) landed own; (k0+64,h0) in flight
    } else {
      VMCNT0();
    }
    BAR();
    {
      bf16x8 fa[8], fb[4];
#pragma unroll
      for (int i = 0; i < 8; i++)
        fa[i] = *(const bf16x8*)(AsW + 4096 + (i * 16 + l16) * 32 + so);
#pragma unroll
      for (int j = 0; j < 4; j++)
        fb[j] =
            *(const bf16x8*)(BsW + 4096 + (64 * hw + j * 16 + l16) * 32 + so);
      LGKM0();
      BAR();                  // h1 reads retired -> h1 free
      if (!lastIt) stageH(k0 + 64, 1);
      __builtin_amdgcn_s_setprio(1);
#pragma unroll
      for (int i = 0; i < 8; i++)
#pragma unroll
        for (int j = 0; j < 4; j++)
          acc[i][j] = __builtin_amdgcn_mfma_f32_16x16x32_bf16(
              fa[i], fb[j], acc[i][j], 0, 0, 0);
      __builtin_amdgcn_s_setprio(0);
    }
  }
  (void)computeH;  // inlined above

  // ---- butterfly epilogue via LDS exchange ----
  // exch layout: f32, addr = col*128 + (row ^ ((col&7)<<2)); 64 KB exact.
  float* exch = (float*)lds;
  BAR();  // everyone past final reads/MFMAs issue; LDS reusable
  if (isO) {
#pragma unroll
    for (int i = 0; i < 8; i++)
#pragma unroll
      for (int j = 0; j < 4; j++) {
        const int col = 64 * hw + j * 16 + l16;
        const int rowb = i * 16 + quad * 4;
        *(f32x4*)(exch + col * 128 + (rowb ^ ((col & 7) << 2))) = acc[i][j];
      }
    LGKM0();
  }
  BAR();  // accO visible collectively
  if (!isO) {
#pragma unroll
    for (int i = 0; i < 8; i++) {
#pragma unroll
      for (int j = 0; j < 4; j++) {
        const int col = 64 * hw + j * 16 + l16;
        const int rowb = i * 16 + quad * 4;
        const f32x4 ov =
            *(const f32x4*)(exch + col * 128 + (rowb ^ ((col & 7) << 2)));
        const int n = n0 + col;
#pragma unroll
        for (int r = 0; r < 4; r++) {
          float e = acc[i][j][r];
          float o = ov[r];
          int m = m0 + rowb + r;
          if (STAGE == 1) {
            unsigned short* mat = (n & 1) ? out1 : out0;
            int c = n >> 1;
            mat[(size_t)m * outStride + c] = f2bf(e + o);
            mat[(size_t)(Lfull - 1 - m) * outStride + c] = f2bf(e - o);
          } else {
            float* y = (float*)out0;
            y[(size_t)m * outStride + n] = e + o;
            y[(size_t)(Lfull - 1 - m) * outStride + n] = o - e;
          }
        }
      }
    }
  }
}

extern "C" void kernel_launch(void* const* d_in, const int* in_sizes, int n_in,
                              void* d_out, int out_size, void* d_ws,
                              size_t ws_size, hipStream_t stream) {
  const float* x = (const float*)d_in[0];
  const int M = in_sizes[1] / 2;  // expkM is [M,2]
  const int N = in_sizes[2] / 2;  // expkN is [N,2]
  const size_t MN = (size_t)M * N;

  // workspace (u16 units), 3*MN u16 = 96 MB @4096:
  //  [0, MN/2)      xe  [M x N/2]
  //  [MN/2, MN)     xo  [M x N/2]
  //  [MN, 5MN/4)    Ce ; [5MN/4, 3MN/2) Co     [N/2 x N/2]
  //  [3MN/2, 7MN/4) Se ; [7MN/4, 2MN)   So     [M/2 x M/2]
  //  [2MN, 5MN/2)   tTe [N x M/2]
  //  [5MN/2, 3MN)   tTo [N x M/2]
  unsigned short* ws = (unsigned short*)d_ws;
  unsigned short* xe = ws;
  unsigned short* xo = ws + MN / 2;
  unsigned short* Ce = ws + MN;
  unsigned short* Co = ws + MN + MN / 4;
  unsigned short* Se = ws + MN * 3 / 2;
  unsigned short* So = ws + MN * 7 / 4;
  unsigned short* tTe = ws + MN * 2;
  unsigned short* tTo = ws + MN * 5 / 2;

  int shiftN = 0; while ((1 << shiftN) < N) shiftN++;
  int shiftM = 0; while ((1 << shiftM) < M) shiftM++;

  // 1: fused prep — convert+deint, gen Ce/Co, gen Se/So
  int nConvBlocks = (int)(MN / 16 / 256);
  int nGenNBlocks = (N / 2) * (N / 2) / 8 / 256;
  int nGenMBlocks = (M / 2) * (M / 2) / 8 / 256;
  prep_kernel<<<nConvBlocks + nGenNBlocks + nGenMBlocks, 256, 0, stream>>>(
      (const f32x4*)x, (u16x8*)xe, (u16x8*)xo, (u16x8*)Ce, (u16x8*)Co,
      (u16x8*)Se, (u16x8*)So, nConvBlocks, nGenNBlocks, shiftN - 4,
      (N / 16) - 1, (unsigned)(4 * N - 1),
      (float)(3.14159265358979323846 / (2.0 * N)), shiftM - 4, (M / 16) - 1,
      (unsigned)(4 * M - 1), (float)(3.14159265358979323846 / (2.0 * M)));

  // 2: F1 — E/O GEMMs (K=N/2) + v-butterfly + p-parity deint -> tTe/tTo
  //    grid: x over p (M/128), y over v' ((N/2)/128); 256 threads
  fused_gemm_kernel<1><<<dim3(M / 128, (N / 2) / 128), 256, 0, stream>>>(
      Ce, Co, xe, xo, tTe, tTo, M / 2, N / 2, N);

  // 3: F2 — E/O GEMMs (K=M/2) + u-butterfly -> y fp32
  //    grid: x over v (N/128), y over u' ((M/2)/128); 256 threads
  fused_gemm_kernel<2><<<dim3(N / 128, (M / 2) / 128), 256, 0, stream>>>(
      Se, So, tTe, tTo, (unsigned short*)d_out, nullptr, N, M / 2, M);
}